// Round 8
// baseline (121.381 us; speedup 1.0000x reference)
//
#include <hip/hip_runtime.h>

// SIAF forward. Round 8 = round-4's verified MFMA math (32 samples/wave, st=2,
// GEMM2 as MFMA vs block-diag c2) + round-7's LDS weight staging (per-block
// 66.5 KB image in final swizzled layout) + swizzled region C (c2) so the
// GEMM2 A-read is 2-way max instead of 16-way.
// Rationale: round 7 was DS-issue-bound (~19 us of per-CU LDS issue); weight
// reads are fixed 48 KB/wave, so amortize over 32 samples not 16, and replace
// the 7 broadcast reads/iter of the FMA-GEMM2 with one c2 read + MFMA.
// TPB 512 (8 waves), grid 512, LDS 130.5 KB -> 1 block/CU.

#define DIMS 64
#define TPB  512

typedef __attribute__((ext_vector_type(8))) short short8;
typedef __attribute__((ext_vector_type(4))) float f32x4;
typedef __attribute__((ext_vector_type(4))) unsigned int uint4v;
typedef unsigned short ushort_t;
typedef unsigned int uint_t;

#if __has_builtin(__builtin_amdgcn_exp2f)
#define YSCALE 2.8853900817779268f      /* 2*log2(e): exp(2y) = exp2(YSCALE*y) */
#define EXPY(x) __builtin_amdgcn_exp2f(x)
#else
#define YSCALE 2.0f
#define EXPY(x) __expf(x)
#endif

// LDS/ws image (bytes), all regions in final swizzled layout:
//  A [0,16384):      w1 rows p<256 (l<32), 64 B/row (k<32), chunk ^= p&3
//  B [16384,49152):  w1 rows 256..511, 128 B/row, chunk ^= p&7
//  C [49152,65536):  c2 bf16 [128 r][64 kl], 128 B/row, chunk ^= r&7
//  D [65536,67584):  b1 fp32 [512] physical-row order, YSCALE-scaled
//  E [67584,68096):  b2 fp32 [64][2]
#define A_OFF 0
#define B_OFF 16384
#define C_OFF 49152
#define D_OFF 65536
#define E_OFF 67584
#define WT_BYTES 68096
#define WT_CHUNKS (WT_BYTES / 16)
#define XZ_OFF WT_BYTES
#define LDS_BYTES (WT_BYTES + 8 * 32 * DIMS * 4)   // 68096 + 65536 = 133632
#define PREP_N (32768 + 640)

__device__ __forceinline__ uint_t pk2bf(float a, float b) {
#if __has_builtin(__builtin_amdgcn_cvt_pk_bf16_f32)
    typedef __attribute__((ext_vector_type(2))) __bf16 bf16x2;
    bf16x2 r = __builtin_amdgcn_cvt_pk_bf16_f32(a, b);
    return __builtin_bit_cast(uint_t, r);
#else
    uint_t ua = __float_as_uint(a); ua += 0x7FFFu + ((ua >> 16) & 1u);
    uint_t ub = __float_as_uint(b); ub += 0x7FFFu + ((ub >> 16) & 1u);
    return (ub & 0xFFFF0000u) | (ua >> 16);
#endif
}

__device__ __forceinline__ ushort_t f2bf(float f) {
    uint_t u = __float_as_uint(f);
    u += 0x7FFFu + ((u >> 16) & 1u);
    return (ushort_t)(u >> 16);
}

// round-4 permutation: physical GEMM1 row p -> logical L (l = L>>3, h = L&7)
__device__ __forceinline__ int logrow(int p) {
    int n = p & 15;
    return (p >> 5) * 32 + (n >> 2) * 8 + ((p >> 4) & 1) * 4 + (n & 3);
}

__global__ void siaf_prep(const float* __restrict__ W1, const float* __restrict__ b1,
                          const float* __restrict__ W2, const float* __restrict__ b2,
                          ushort_t* __restrict__ ws_u) {
    int i = blockIdx.x * 256 + threadIdx.x;
    if (i < 8192) {                       // region A: p<256, 32 ushorts/row
        int p = i >> 5, e = i & 31;
        int cp = e >> 3, j = e & 7;
        int k = ((cp ^ (p & 3)) << 3) | j;
        int L = logrow(p), l = L >> 3, h = L & 7;
        float v = (k <= l) ? W1[(l * 8 + h) * 63 + k] * YSCALE : 0.0f;
        ws_u[i] = f2bf(v);
    } else if (i < 24576) {               // region B: p in [256,512), 64 ushorts/row
        int v_ = i - 8192;
        int p = 256 + (v_ >> 6), e = v_ & 63;
        int cp = e >> 3, j = e & 7;
        int k = ((cp ^ (p & 7)) << 3) | j;
        int L = logrow(p), l = L >> 3, h = L & 7;
        float v = (l < 63 && k <= l) ? W1[(l * 8 + h) * 63 + k] * YSCALE : 0.0f;
        ws_u[i] = f2bf(v);
    } else if (i < 32768) {               // region C: c2, 64 ushorts/row, chunk^=r&7
        int j_ = i - 24576;
        int r = j_ >> 6, e = j_ & 63;
        int cp = e >> 3, jj = e & 7;
        int kl = ((cp ^ (r & 7)) << 3) | jj;
        int l = r >> 1, o = r & 1;
        float v = 0.0f;
        if (l < 63 && (kl >> 3) == (l & 7)) v = W2[(l * 2 + o) * 8 + (kl & 7)];
        ws_u[i] = f2bf(v);
    } else if (i < PREP_N) {              // fp32 regions D/E
        int f = i - 32768;
        float* fws = (float*)(ws_u + 32768);
        float v = 0.0f;
        if (f < 512) {                    // D: b1 in physical row order
            int L = logrow(f), l = L >> 3, h = L & 7;
            if (l < 63) v = b1[l * 8 + h] * YSCALE;
        } else {                          // E: b2 [l][o]
            int j = f - 512, l = j >> 1, o = j & 1;
            if (l < 63) v = b2[l * 2 + o];
        }
        fws[f] = v;
    }
}

__device__ __forceinline__ float th(float t) {
    // t = YSCALE*y ; tanh(y) = 1 - 2/(exp2(t)+1)
    float e = EXPY(t);
    float r = __builtin_amdgcn_rcpf(e + 1.0f);
    return fmaf(-2.0f, r, 1.0f);
}

__global__ __launch_bounds__(TPB, 2) void siaf_main(
        const float* __restrict__ x, const float* __restrict__ ip,
        const uint4* __restrict__ wsv, float* __restrict__ out, int nB) {
    extern __shared__ unsigned char lds[];

    // ---- stage the 66.5 KB weight image (already in final layout) ----
    {
        uint4* dst = (uint4*)lds;
        for (int c = threadIdx.x; c < WT_CHUNKS; c += TPB) dst[c] = wsv[c];
    }
    __syncthreads();

    const ushort_t* wA  = (const ushort_t*)(lds + A_OFF);
    const ushort_t* wB  = (const ushort_t*)(lds + B_OFF);
    const ushort_t* wC  = (const ushort_t*)(lds + C_OFF);
    const float*    b1f = (const float*)(lds + D_OFF);
    const float*    b2f = (const float*)(lds + E_OFF);

    const int tid  = threadIdx.x;
    const int wv   = tid >> 6, lane = tid & 63;
    const int s16  = lane & 15, quad = lane >> 4;
    const int sbase = blockIdx.x * 256 + wv * 32;
    float* xzw = (float*)(lds + XZ_OFF) + wv * (32 * DIMS);

    // ---- stage x: coalesced 1KB/instr, 16B-chunk XOR swizzle ----
    #pragma unroll
    for (int g = 0; g < 8; ++g) {
        const float4 v = ((const float4*)(x + (size_t)(sbase + 4 * g) * DIMS))[lane];
        const int s_loc = 4 * g + quad;
        const int chunk = s16 ^ (s_loc & 15);
        *(float4*)(xzw + s_loc * 64 + chunk * 4) = v;
    }
    const float ip0 = ip[0], ip1 = ip[1];

    // ---- x B-frags (bf16) from LDS ----
    short8 bfr[2][2];
    float lsum[2] = {0.0f, 0.0f};
    #pragma unroll
    for (int st = 0; st < 2; ++st) {
        const int s_loc = st * 16 + s16;
        #pragma unroll
        for (int kh = 0; kh < 2; ++kh) {
            const int c0 = kh * 8 + quad * 2;
            float4 va = *(const float4*)(xzw + s_loc * 64 + ((c0 ^ s16) & 15) * 4);
            float4 vb = *(const float4*)(xzw + s_loc * 64 + (((c0 + 1) ^ s16) & 15) * 4);
            uint4v u = {pk2bf(va.x, va.y), pk2bf(va.z, va.w),
                        pk2bf(vb.x, vb.y), pk2bf(vb.z, vb.w)};
            bfr[st][kh] = __builtin_bit_cast(short8, u);
        }
    }

    #pragma unroll
    for (int mt = 0; mt < 8; ++mt) {
        f32x4 acc2[2] = {{0.f, 0.f, 0.f, 0.f}, {0.f, 0.f, 0.f, 0.f}};

        #pragma unroll
        for (int half = 0; half < 2; ++half) {
            const int g = 2 * mt + half;
            const int p0 = 2 * g;
            // A-frags from LDS (swizzled regions)
            short8 a00, a10, a01{}, a11{};
            if (g < 8) {
                const ushort_t* rowp = wA + (g * 32 + s16) * 32;
                const int pc = quad ^ (s16 & 3);
                a00 = *(const short8*)(rowp + pc * 8);
                a10 = *(const short8*)(rowp + 512 + pc * 8);
            } else {
                const ushort_t* rowp = wB + ((g - 8) * 32 + s16) * 64;
                const int pc = quad ^ (s16 & 7);
                a00 = *(const short8*)(rowp + pc * 8);
                a10 = *(const short8*)(rowp + 1024 + pc * 8);
                a01 = *(const short8*)(rowp + (pc ^ 4) * 8);
                a11 = *(const short8*)(rowp + 1024 + (pc ^ 4) * 8);
            }
            const float4 bi0 = *(const float4*)(b1f + p0 * 16 + quad * 4);        // bcast
            const float4 bi1 = *(const float4*)(b1f + (p0 + 1) * 16 + quad * 4);  // bcast
            const short8 c2 = *(const short8*)(
                wC + (mt * 16 + s16) * 64 + ((half * 4 + quad) ^ (s16 & 7)) * 8);

            #pragma unroll
            for (int st = 0; st < 2; ++st) {
                f32x4 aE = {bi0.x, bi0.y, bi0.z, bi0.w};
                f32x4 aO = {bi1.x, bi1.y, bi1.z, bi1.w};
                aE = __builtin_amdgcn_mfma_f32_16x16x32_bf16(a00, bfr[st][0], aE, 0, 0, 0);
                aO = __builtin_amdgcn_mfma_f32_16x16x32_bf16(a10, bfr[st][0], aO, 0, 0, 0);
                if (g >= 8) {
                    aE = __builtin_amdgcn_mfma_f32_16x16x32_bf16(a01, bfr[st][1], aE, 0, 0, 0);
                    aO = __builtin_amdgcn_mfma_f32_16x16x32_bf16(a11, bfr[st][1], aO, 0, 0, 0);
                }
                // lane's own accs ARE its GEMM2 B-frag (row permutation in prep)
                uint4v hh = {pk2bf(th(aE[0]), th(aE[1])), pk2bf(th(aE[2]), th(aE[3])),
                             pk2bf(th(aO[0]), th(aO[1])), pk2bf(th(aO[2]), th(aO[3]))};
                const short8 hfr = __builtin_bit_cast(short8, hh);
                acc2[st] = __builtin_amdgcn_mfma_f32_16x16x32_bf16(c2, hfr, acc2[st], 0, 0, 0);
            }
        }

        // ---- epilogue for l = mt*8 .. mt*8+7: z in-place in LDS ----
        const int l0 = mt * 8 + quad * 2;
        const float4 b2v = *(const float4*)(b2f + l0 * 2);    // bcast
        const bool pad = (l0 == 62);            // l=63 slot handles d=0 instead
        #pragma unroll
        for (int st = 0; st < 2; ++st) {
            const int s_loc = st * 16 + s16;
            float mu0 = acc2[st][0] + b2v.x, al0 = acc2[st][1] + b2v.y;
            float mu1 = acc2[st][2] + b2v.z, al1 = acc2[st][3] + b2v.w;
            const int d1 = l0 + 1;
            float* p1 = xzw + s_loc * 64 + (((((d1 >> 2) ^ s16) & 15) << 2) | (d1 & 3));
            *p1 = fmaf(*p1, __expf(al0), mu0);
            lsum[st] += al0;
            const float alB = pad ? ip1 : al1;
            const float muB = pad ? ip0 : mu1;
            const int d2 = pad ? 0 : (l0 + 2);
            float* p2 = xzw + s_loc * 64 + (((((d2 >> 2) ^ s16) & 15) << 2) | (d2 & 3));
            *p2 = fmaf(*p2, __expf(alB), muB);
            lsum[st] += alB;
        }
    }

    // ---- coalesced LDS -> global z store ----
    #pragma unroll
    for (int g = 0; g < 8; ++g) {
        const int s_loc = 4 * g + quad;
        const int chunk = s16 ^ (s_loc & 15);
        const float4 v = *(const float4*)(xzw + s_loc * 64 + chunk * 4);
        ((float4*)(out + (size_t)(sbase + 4 * g) * DIMS))[lane] = v;
    }

    // ---- log_det: sum the 4 quad-partials per sample ----
    #pragma unroll
    for (int st = 0; st < 2; ++st) {
        float v = lsum[st];
        int r1 = __builtin_amdgcn_ds_swizzle(__float_as_int(v), 0x401F);  // xor 16
        v += __int_as_float(r1);
        int r2 = __builtin_amdgcn_ds_bpermute((lane ^ 32) << 2, __float_as_int(v));
        v += __int_as_float(r2);
        if (quad == 0)
            out[(size_t)nB * DIMS + sbase + st * 16 + s16] = v;
    }
}

extern "C" void kernel_launch(void* const* d_in, const int* in_sizes, int n_in,
                              void* d_out, int out_size, void* d_ws, size_t ws_size,
                              hipStream_t stream) {
    const float* x  = (const float*)d_in[0];
    const float* ip = (const float*)d_in[1];
    const float* W1 = (const float*)d_in[2];
    const float* b1 = (const float*)d_in[3];
    const float* W2 = (const float*)d_in[4];
    const float* b2 = (const float*)d_in[5];
    ushort_t* ws = (ushort_t*)d_ws;
    float* out = (float*)d_out;
    (void)ws_size;

    const int nB = in_sizes[0] / DIMS;      // 131072

    (void)hipFuncSetAttribute((const void*)siaf_main,
                              hipFuncAttributeMaxDynamicSharedMemorySize, LDS_BYTES);

    siaf_prep<<<(PREP_N + 255) / 256, 256, 0, stream>>>(W1, b1, W2, b2, ws);
    siaf_main<<<nB / 256, TPB, LDS_BYTES, stream>>>(x, ip, (const uint4*)ws, out, nB);
}